// Round 1
// baseline (427.775 us; speedup 1.0000x reference)
//
#include <hip/hip_runtime.h>
#include <hip/hip_bf16.h>

// Problem constants
#define S_      1024
#define B_      2
#define H_      1024
#define E_      8
#define FFN_    1408
#define TWO_FFN 2816
#define T_      2048          // B_*S_
#define MAXSLOTS 5120         // 4096 gathered rows + up to 8*127 padding, rounded to 40*128
#define MAXTILES 40

typedef float  f32x4 __attribute__((ext_vector_type(4)));
typedef short  s16x8 __attribute__((ext_vector_type(8)));

// ---------- helpers ----------
__device__ __forceinline__ unsigned short f2bf(float f) {
    unsigned u = __float_as_uint(f);
    u += 0x7fffu + ((u >> 16) & 1u);          // round-to-nearest-even
    return (unsigned short)(u >> 16);
}
__device__ __forceinline__ float bf2f(unsigned short h) {
    return __uint_as_float(((unsigned)h) << 16);
}
// async global->LDS, 16B per lane. LDS dst is wave-uniform base + lane*16;
// we pass base+lane*16 per lane so lane0's value is the base (consistent either way).
__device__ __forceinline__ void async16(const void* g, void* l) {
    __builtin_amdgcn_global_load_lds(
        (const __attribute__((address_space(1))) unsigned int*)(unsigned long long)g,
        (__attribute__((address_space(3))) unsigned int*)(unsigned long long)l,
        16, 0, 0);
}

// x row base offset in hidden_states for token t (t = b*S + s)
__device__ __forceinline__ size_t xrow_off(int t) {
    return (size_t)(t & (S_ - 1)) * (B_ * H_) + (size_t)(t >> 10) * H_;
}

// ---------- 1. convert x (with [S,B,H]->[T,H] permute) ----------
__global__ void k_convert_x(const float* __restrict__ hs, unsigned short* __restrict__ xb) {
    int gid  = blockIdx.x * 256 + threadIdx.x;   // 524288 threads, 4 elems each
    int idx4 = gid * 4;
    int t = idx4 >> 10;
    int h = idx4 & 1023;
    const float4 v = *(const float4*)(hs + xrow_off(t) + h);
    unsigned short o[4] = { f2bf(v.x), f2bf(v.y), f2bf(v.z), f2bf(v.w) };
    *(uint2*)(xb + (size_t)t * H_ + h) = *(const uint2*)o;
}

// ---------- 2. transpose+convert weights: out[e][c][r] = bf16(in[e][r][c]) ----------
__global__ void k_transpose_bf16(const float* __restrict__ in, unsigned short* __restrict__ out,
                                 int R, int C) {
    __shared__ float tile[32][33];
    int e = blockIdx.z;
    const float* ip = in + (size_t)e * R * C;
    unsigned short* op = out + (size_t)e * R * C;
    int c0 = blockIdx.x * 32, r0 = blockIdx.y * 32;
    int tx = threadIdx.x, ty = threadIdx.y;   // 32 x 8
#pragma unroll
    for (int i = 0; i < 4; i++)
        tile[ty + i * 8][tx] = ip[(size_t)(r0 + ty + i * 8) * C + c0 + tx];
    __syncthreads();
#pragma unroll
    for (int i = 0; i < 4; i++)
        op[(size_t)(c0 + ty + i * 8) * R + r0 + tx] = f2bf(tile[tx][ty + i * 8]);
}

// ---------- 3. gate: fp32 logits, softmax top-2, normalized weights ----------
__global__ void k_gate(const float* __restrict__ hs, const float* __restrict__ gw,
                       int* __restrict__ topkI, float* __restrict__ topkW,
                       int* __restrict__ ctrl) {
    int wid = threadIdx.x >> 6, lane = threadIdx.x & 63;
    int t = blockIdx.x * 4 + wid;                 // grid = 512 -> 2048 tokens
    const float* xr = hs + xrow_off(t);
    float acc[E_];
#pragma unroll
    for (int e = 0; e < E_; e++) acc[e] = 0.f;
    for (int h = lane; h < H_; h += 64) {
        float xv = xr[h];
#pragma unroll
        for (int e = 0; e < E_; e++) acc[e] += xv * gw[e * H_ + h];
    }
#pragma unroll
    for (int e = 0; e < E_; e++)
        for (int off = 32; off > 0; off >>= 1) acc[e] += __shfl_down(acc[e], off);
    if (lane == 0) {
        float l0 = -1e30f, l1 = -1e30f; int i0 = 0, i1 = 0;
#pragma unroll
        for (int e = 0; e < E_; e++) {
            float v = acc[e];
            if (v > l0)      { l1 = l0; i1 = i0; l0 = v; i0 = e; }
            else if (v > l1) { l1 = v;  i1 = e; }
        }
        float p1 = expf(l1 - l0);                 // p0 = 1
        float w0 = 1.f / (1.f + p1);
        float w1 = 1.f - w0;
        topkI[2 * t] = i0; topkI[2 * t + 1] = i1;
        topkW[2 * t] = w0; topkW[2 * t + 1] = w1;
        atomicAdd(&ctrl[i0], 1);                  // counts at ctrl[0..7]
        atomicAdd(&ctrl[i1], 1);
    }
}

// ---------- 4. build routing tables (1 block) ----------
// ctrl layout (ints): [0..7]=cnt  [8..15]=cursor  [16..23]=base  [24]=nTiles [25]=totSlots
//                     [32..95]=tileExpert  [96..159]=tileSlotBase
__global__ void k_route(int* __restrict__ ctrl, int* __restrict__ perm, float* __restrict__ wgt) {
    if (threadIdx.x == 0) {
        int b = 0, nt = 0;
        for (int e = 0; e < E_; e++) {
            ctrl[16 + e] = b;
            int n = ctrl[e];
            int ntile = (n + 127) >> 7;
            for (int ti = 0; ti < ntile; ti++) { ctrl[32 + nt] = e; ctrl[96 + nt] = b + ti * 128; nt++; }
            b += ntile * 128;
        }
        ctrl[24] = nt;
        ctrl[25] = b;
    }
    __syncthreads();
    for (int s = threadIdx.x; s < MAXSLOTS; s += blockDim.x) { perm[s] = 0; wgt[s] = 0.f; }
}

// ---------- 5. assign tokens to slots ----------
__global__ void k_assign(const int* __restrict__ topkI, const float* __restrict__ topkW,
                         int* __restrict__ ctrl, int* __restrict__ perm, float* __restrict__ wgt) {
    int t = blockIdx.x * 256 + threadIdx.x;
    if (t >= T_) return;
#pragma unroll
    for (int k = 0; k < 2; k++) {
        int e = topkI[2 * t + k];
        int pos = atomicAdd(&ctrl[8 + e], 1);
        int slot = ctrl[16 + e] + pos;
        perm[slot] = t;
        wgt[slot]  = topkW[2 * t + k];
    }
}

// ---------- 6. GEMM1: Xg[128,1024] @ w1bt^T -> C1 bf16 [slot][2816] ----------
__global__ __launch_bounds__(256) void k_gemm1(
    const unsigned short* __restrict__ xb, const unsigned short* __restrict__ w1bt,
    const int* __restrict__ ctrl, const int* __restrict__ perm,
    unsigned short* __restrict__ C1) {
    int nt = ctrl[24];
    int tileIdx = blockIdx.x;
    if (tileIdx >= nt) return;
    int e     = ctrl[32 + tileIdx];
    int slot0 = ctrl[96 + tileIdx];
    int ct    = blockIdx.y;                     // 0..21 column tiles of 128
    __shared__ unsigned short As[128 * 64];
    __shared__ unsigned short Bs[128 * 64];
    int tid = threadIdx.x, wid = tid >> 6, lane = tid & 63;

    const unsigned short* aPtr[4];
    const unsigned short* bPtr[4];
    unsigned short* lA[4];
    unsigned short* lB[4];
#pragma unroll
    for (int i = 0; i < 4; i++) {
        int c = (wid * 4 + i) * 64 + lane;      // chunk id 0..1023
        int r = c >> 3, col8 = (c & 7) * 8;
        int tok = perm[slot0 + r];
        aPtr[i] = xb + (size_t)tok * H_ + col8;
        bPtr[i] = w1bt + ((size_t)e * TWO_FFN + ct * 128 + r) * H_ + col8;
        lA[i] = As + (size_t)c * 8;
        lB[i] = Bs + (size_t)c * 8;
    }
    f32x4 acc[4][4];
#pragma unroll
    for (int mi = 0; mi < 4; mi++)
#pragma unroll
        for (int ni = 0; ni < 4; ni++) acc[mi][ni] = (f32x4){0.f, 0.f, 0.f, 0.f};
    int wm = wid & 1, wn = wid >> 1;
    int rowB = wm * 64, colB = wn * 64;

    for (int k0 = 0; k0 < H_; k0 += 64) {
#pragma unroll
        for (int i = 0; i < 4; i++) { async16(aPtr[i] + k0, lA[i]); async16(bPtr[i] + k0, lB[i]); }
        __syncthreads();
#pragma unroll
        for (int kk = 0; kk < 64; kk += 32) {
            int kr = kk + (lane >> 4) * 8;
            s16x8 af[4], bf[4];
#pragma unroll
            for (int mi = 0; mi < 4; mi++) af[mi] = *(const s16x8*)&As[(rowB + mi * 16 + (lane & 15)) * 64 + kr];
#pragma unroll
            for (int ni = 0; ni < 4; ni++) bf[ni] = *(const s16x8*)&Bs[(colB + ni * 16 + (lane & 15)) * 64 + kr];
#pragma unroll
            for (int mi = 0; mi < 4; mi++)
#pragma unroll
                for (int ni = 0; ni < 4; ni++)
                    acc[mi][ni] = __builtin_amdgcn_mfma_f32_16x16x32_bf16(af[mi], bf[ni], acc[mi][ni], 0, 0, 0);
        }
        __syncthreads();
    }
#pragma unroll
    for (int mi = 0; mi < 4; mi++)
#pragma unroll
        for (int ni = 0; ni < 4; ni++)
#pragma unroll
            for (int r = 0; r < 4; r++) {
                int m = rowB + mi * 16 + (lane >> 4) * 4 + r;
                int n = colB + ni * 16 + (lane & 15);
                C1[(size_t)(slot0 + m) * TWO_FFN + ct * 128 + n] = f2bf(acc[mi][ni][r]);
            }
}

// ---------- 7. swiglu: A2[slot][j] = silu(g)*u ----------
__global__ void k_swiglu(const unsigned short* __restrict__ C1, unsigned short* __restrict__ A2) {
    int gid = blockIdx.x * 256 + threadIdx.x;   // 5120*352 threads, 4 j's each
    int row = gid / 352;
    int j   = (gid - row * 352) * 4;
    const unsigned short* g = C1 + (size_t)row * TWO_FFN + j;
    unsigned short o[4];
#pragma unroll
    for (int i = 0; i < 4; i++) {
        float gv = bf2f(g[i]);
        float uv = bf2f(g[i + FFN_]);
        float s = gv / (1.f + expf(-gv));
        o[i] = f2bf(s * uv);
    }
    *(uint2*)(A2 + (size_t)row * FFN_ + j) = *(const uint2*)o;
}

// ---------- 8. GEMM2: A2[128,1408] @ w2bt^T, scale by gate weight, scatter-add ----------
__global__ __launch_bounds__(256) void k_gemm2(
    const unsigned short* __restrict__ A2, const unsigned short* __restrict__ w2bt,
    const int* __restrict__ ctrl, const int* __restrict__ perm, const float* __restrict__ wgt,
    float* __restrict__ out) {
    int nt = ctrl[24];
    int tileIdx = blockIdx.x;
    if (tileIdx >= nt) return;
    int e     = ctrl[32 + tileIdx];
    int slot0 = ctrl[96 + tileIdx];
    int ct    = blockIdx.y;                     // 0..7 column tiles of 128 over H
    __shared__ unsigned short As[128 * 64];
    __shared__ unsigned short Bs[128 * 64];
    int tid = threadIdx.x, wid = tid >> 6, lane = tid & 63;

    const unsigned short* aPtr[4];
    const unsigned short* bPtr[4];
    unsigned short* lA[4];
    unsigned short* lB[4];
#pragma unroll
    for (int i = 0; i < 4; i++) {
        int c = (wid * 4 + i) * 64 + lane;
        int r = c >> 3, col8 = (c & 7) * 8;
        aPtr[i] = A2 + (size_t)(slot0 + r) * FFN_ + col8;
        bPtr[i] = w2bt + ((size_t)e * H_ + ct * 128 + r) * FFN_ + col8;
        lA[i] = As + (size_t)c * 8;
        lB[i] = Bs + (size_t)c * 8;
    }
    f32x4 acc[4][4];
#pragma unroll
    for (int mi = 0; mi < 4; mi++)
#pragma unroll
        for (int ni = 0; ni < 4; ni++) acc[mi][ni] = (f32x4){0.f, 0.f, 0.f, 0.f};
    int wm = wid & 1, wn = wid >> 1;
    int rowB = wm * 64, colB = wn * 64;

    for (int k0 = 0; k0 < FFN_; k0 += 64) {     // 22 steps
#pragma unroll
        for (int i = 0; i < 4; i++) { async16(aPtr[i] + k0, lA[i]); async16(bPtr[i] + k0, lB[i]); }
        __syncthreads();
#pragma unroll
        for (int kk = 0; kk < 64; kk += 32) {
            int kr = kk + (lane >> 4) * 8;
            s16x8 af[4], bf[4];
#pragma unroll
            for (int mi = 0; mi < 4; mi++) af[mi] = *(const s16x8*)&As[(rowB + mi * 16 + (lane & 15)) * 64 + kr];
#pragma unroll
            for (int ni = 0; ni < 4; ni++) bf[ni] = *(const s16x8*)&Bs[(colB + ni * 16 + (lane & 15)) * 64 + kr];
#pragma unroll
            for (int mi = 0; mi < 4; mi++)
#pragma unroll
                for (int ni = 0; ni < 4; ni++)
                    acc[mi][ni] = __builtin_amdgcn_mfma_f32_16x16x32_bf16(af[mi], bf[ni], acc[mi][ni], 0, 0, 0);
        }
        __syncthreads();
    }
#pragma unroll
    for (int mi = 0; mi < 4; mi++)
#pragma unroll
        for (int r = 0; r < 4; r++) {
            int m = rowB + mi * 16 + (lane >> 4) * 4 + r;
            int slot = slot0 + m;
            int tok = perm[slot];
            float wv = wgt[slot];
            size_t obase = xrow_off(tok);
#pragma unroll
            for (int ni = 0; ni < 4; ni++) {
                int n = colB + ni * 16 + (lane & 15);
                atomicAdd(&out[obase + ct * 128 + n], acc[mi][ni][r] * wv);
            }
        }
}

extern "C" void kernel_launch(void* const* d_in, const int* in_sizes, int n_in,
                              void* d_out, int out_size, void* d_ws, size_t ws_size,
                              hipStream_t stream) {
    (void)in_sizes; (void)n_in; (void)ws_size;
    const float* hs = (const float*)d_in[0];
    const float* gw = (const float*)d_in[1];
    const float* w1 = (const float*)d_in[2];
    const float* w2 = (const float*)d_in[3];
    float* out = (float*)d_out;
    char* ws = (char*)d_ws;

    int*            ctrl  = (int*)ws;                                   // 4 KB
    int*            topkI = (int*)(ws + (16u << 10));                   // 16 KB
    float*          topkW = (float*)(ws + (48u << 10));                 // 16 KB
    int*            perm  = (int*)(ws + (80u << 10));                   // 20 KB
    float*          wgt   = (float*)(ws + (112u << 10));                // 20 KB
    unsigned short* xb    = (unsigned short*)(ws + (1ull  << 20));      // 4 MiB
    unsigned short* w1bt  = (unsigned short*)(ws + (5ull  << 20));      // 44 MiB
    unsigned short* w2bt  = (unsigned short*)(ws + (49ull << 20));      // 22 MiB
    unsigned short* C1    = (unsigned short*)(ws + (71ull << 20));      // 27.5 MiB
    unsigned short* A2    = (unsigned short*)(ws + (99ull << 20));      // 13.75 MiB -> end 113 MiB

    hipMemsetAsync(ctrl, 0, 1024, stream);
    hipMemsetAsync(d_out, 0, (size_t)out_size * sizeof(float), stream);

    k_convert_x<<<2048, 256, 0, stream>>>(hs, xb);
    k_transpose_bf16<<<dim3(TWO_FFN / 32, H_ / 32, E_), dim3(32, 8), 0, stream>>>(w1, w1bt, H_, TWO_FFN);
    k_transpose_bf16<<<dim3(H_ / 32, FFN_ / 32, E_), dim3(32, 8), 0, stream>>>(w2, w2bt, FFN_, H_);
    k_gate<<<512, 256, 0, stream>>>(hs, gw, topkI, topkW, ctrl);
    k_route<<<1, 256, 0, stream>>>(ctrl, perm, wgt);
    k_assign<<<8, 256, 0, stream>>>(topkI, topkW, ctrl, perm, wgt);
    k_gemm1<<<dim3(MAXTILES, TWO_FFN / 128), 256, 0, stream>>>(xb, w1bt, ctrl, perm, C1);
    k_swiglu<<<7040, 256, 0, stream>>>(C1, A2);
    k_gemm2<<<dim3(MAXTILES, H_ / 128), 256, 0, stream>>>(A2, w2bt, ctrl, perm, wgt, out);
}

// Round 2
// 334.510 us; speedup vs baseline: 1.2788x; 1.2788x over previous
//
#include <hip/hip_runtime.h>
#include <hip/hip_bf16.h>

// Problem constants
#define S_      1024
#define B_      2
#define H_      1024
#define E_      8
#define FFN_    1408
#define TWO_FFN 2816
#define T_      2048          // B_*S_
#define MAXSLOTS 5120         // >= 39 tiles * 128
#define MAXTILES 40

typedef float  f32x4 __attribute__((ext_vector_type(4)));
typedef short  s16x8 __attribute__((ext_vector_type(8)));

// ---------- helpers ----------
__device__ __forceinline__ unsigned short f2bf(float f) {
    unsigned u = __float_as_uint(f);
    u += 0x7fffu + ((u >> 16) & 1u);          // round-to-nearest-even
    return (unsigned short)(u >> 16);
}
__device__ __forceinline__ float bf2f(unsigned short h) {
    return __uint_as_float(((unsigned)h) << 16);
}
__device__ __forceinline__ void async16(const void* g, void* l) {
    __builtin_amdgcn_global_load_lds(
        (const __attribute__((address_space(1))) unsigned int*)(unsigned long long)g,
        (__attribute__((address_space(3))) unsigned int*)(unsigned long long)l,
        16, 0, 0);
}
__device__ __forceinline__ size_t xrow_off(int t) {
    return (size_t)(t & (S_ - 1)) * (B_ * H_) + (size_t)(t >> 10) * H_;
}

// ---------- 1. fused convert x (permute [S,B,H]->[T,H], fp32->bf16) + gate top-2 ----------
__global__ void k_convert_gate(const float* __restrict__ hs, const float* __restrict__ gw,
                               unsigned short* __restrict__ xb,
                               int* __restrict__ topkI, float* __restrict__ topkW,
                               int* __restrict__ ctrl) {
    int wid = threadIdx.x >> 6, lane = threadIdx.x & 63;
    int t = blockIdx.x * 4 + wid;                 // 512 blocks -> 2048 tokens
    const float* xr = hs + xrow_off(t);
    unsigned short* xo = xb + (size_t)t * H_;
    float acc[E_];
#pragma unroll
    for (int e = 0; e < E_; e++) acc[e] = 0.f;
#pragma unroll
    for (int p = 0; p < 4; p++) {
        int h = p * 256 + lane * 4;
        const float4 v = *(const float4*)(xr + h);
        unsigned short o[4] = { f2bf(v.x), f2bf(v.y), f2bf(v.z), f2bf(v.w) };
        *(uint2*)(xo + h) = *(const uint2*)o;
#pragma unroll
        for (int e = 0; e < E_; e++) {
            const float4 g = *(const float4*)(gw + e * H_ + h);
            acc[e] += v.x * g.x + v.y * g.y + v.z * g.z + v.w * g.w;
        }
    }
#pragma unroll
    for (int e = 0; e < E_; e++)
        for (int off = 32; off > 0; off >>= 1) acc[e] += __shfl_down(acc[e], off);
    if (lane == 0) {
        float l0 = -1e30f, l1 = -1e30f; int i0 = 0, i1 = 0;
#pragma unroll
        for (int e = 0; e < E_; e++) {
            float v = acc[e];
            if (v > l0)      { l1 = l0; i1 = i0; l0 = v; i0 = e; }
            else if (v > l1) { l1 = v;  i1 = e; }
        }
        float p1 = expf(l1 - l0);                 // p0 = 1
        float w0 = 1.f / (1.f + p1);
        float w1 = 1.f - w0;
        topkI[2 * t] = i0; topkI[2 * t + 1] = i1;
        topkW[2 * t] = w0; topkW[2 * t + 1] = w1;
        atomicAdd(&ctrl[i0], 1);
        atomicAdd(&ctrl[i1], 1);
    }
}

// ---------- 2. transpose+convert weights: out[e][c][r] = bf16(in[e][r][c]) ----------
__global__ void k_transpose_bf16(const float* __restrict__ in, unsigned short* __restrict__ out,
                                 int R, int C) {
    __shared__ float tile[32][33];
    int e = blockIdx.z;
    const float* ip = in + (size_t)e * R * C;
    unsigned short* op = out + (size_t)e * R * C;
    int c0 = blockIdx.x * 32, r0 = blockIdx.y * 32;
    int tx = threadIdx.x, ty = threadIdx.y;   // 32 x 8
#pragma unroll
    for (int i = 0; i < 4; i++)
        tile[ty + i * 8][tx] = ip[(size_t)(r0 + ty + i * 8) * C + c0 + tx];
    __syncthreads();
#pragma unroll
    for (int i = 0; i < 4; i++)
        op[(size_t)(c0 + ty + i * 8) * R + r0 + tx] = f2bf(tile[tx][ty + i * 8]);
}

// ---------- 3. fused route + assign (one block, LDS cursors) ----------
// ctrl ints: [0..7]=cnt [24]=nTiles [32..95]=tileExpert [96..159]=tileSlotBase
__global__ void k_routeassign(const int* __restrict__ topkI, const float* __restrict__ topkW,
                              int* __restrict__ ctrl, int* __restrict__ perm,
                              float* __restrict__ wgt, int* __restrict__ slotOfTok) {
    __shared__ int s_base[E_];
    __shared__ int s_cur[E_];
    int tid = threadIdx.x;
    if (tid == 0) {
        int cnt[E_];
#pragma unroll
        for (int e = 0; e < E_; e++) cnt[e] = ctrl[e];
        int b = 0, nt = 0;
        for (int e = 0; e < E_; e++) {
            s_base[e] = b;
            int ntile = (cnt[e] + 127) >> 7;
            for (int ti = 0; ti < ntile; ti++) { ctrl[32 + nt] = e; ctrl[96 + nt] = b + ti * 128; nt++; }
            b += ntile * 128;
        }
        ctrl[24] = nt;
#pragma unroll
        for (int e = 0; e < E_; e++) s_cur[e] = 0;
    }
    __syncthreads();
    for (int s = tid; s < MAXSLOTS; s += 256) { perm[s] = 0; wgt[s] = 0.f; }
    __syncthreads();
    for (int t = tid; t < T_; t += 256) {
#pragma unroll
        for (int k = 0; k < 2; k++) {
            int e = topkI[2 * t + k];
            int pos = atomicAdd(&s_cur[e], 1);
            int slot = s_base[e] + pos;
            perm[slot] = t;
            wgt[slot]  = topkW[2 * t + k];
            slotOfTok[2 * t + k] = slot;
        }
    }
}

// ---------- 4. GEMM1: Xg[128,1024] @ w1bt^T -> C1 bf16 [slot][2816]  (XOR-swizzled LDS) ----------
__global__ __launch_bounds__(256) void k_gemm1(
    const unsigned short* __restrict__ xb, const unsigned short* __restrict__ w1bt,
    const int* __restrict__ ctrl, const int* __restrict__ perm,
    unsigned short* __restrict__ C1) {
    int nt = ctrl[24];
    int tileIdx = blockIdx.x;
    if (tileIdx >= nt) return;
    int e     = ctrl[32 + tileIdx];
    int slot0 = ctrl[96 + tileIdx];
    int ct    = blockIdx.y;                     // 0..21 column tiles of 128
    __shared__ unsigned short As[128 * 64];
    __shared__ unsigned short Bs[128 * 64];
    int tid = threadIdx.x, wid = tid >> 6, lane = tid & 63;

    const unsigned short* aPtr[4];
    const unsigned short* bPtr[4];
    unsigned short* lA[4];
    unsigned short* lB[4];
#pragma unroll
    for (int i = 0; i < 4; i++) {
        int c = (wid * 4 + i) * 64 + lane;      // chunk id 0..1023
        int r = c >> 3;
        int qd = (c & 7) ^ (r & 7);             // XOR swizzle: slot q holds data chunk q^(r&7)
        int col8 = qd * 8;
        int tok = perm[slot0 + r];
        aPtr[i] = xb + (size_t)tok * H_ + col8;
        bPtr[i] = w1bt + ((size_t)e * TWO_FFN + ct * 128 + r) * H_ + col8;
        lA[i] = As + (size_t)c * 8;
        lB[i] = Bs + (size_t)c * 8;
    }
    f32x4 acc[4][4];
#pragma unroll
    for (int mi = 0; mi < 4; mi++)
#pragma unroll
        for (int ni = 0; ni < 4; ni++) acc[mi][ni] = (f32x4){0.f, 0.f, 0.f, 0.f};
    int wm = wid & 1, wn = wid >> 1;
    int rowB = wm * 64, colB = wn * 64;
    int sw = (lane & 7) << 3;                   // read-side swizzle (R&7 == lane&7)

    for (int k0 = 0; k0 < H_; k0 += 64) {
#pragma unroll
        for (int i = 0; i < 4; i++) { async16(aPtr[i] + k0, lA[i]); async16(bPtr[i] + k0, lB[i]); }
        __syncthreads();
#pragma unroll
        for (int kk = 0; kk < 64; kk += 32) {
            int kr = (kk + ((lane >> 4) << 3)) ^ sw;
            s16x8 af[4], bf[4];
#pragma unroll
            for (int mi = 0; mi < 4; mi++) af[mi] = *(const s16x8*)&As[(rowB + mi * 16 + (lane & 15)) * 64 + kr];
#pragma unroll
            for (int ni = 0; ni < 4; ni++) bf[ni] = *(const s16x8*)&Bs[(colB + ni * 16 + (lane & 15)) * 64 + kr];
#pragma unroll
            for (int mi = 0; mi < 4; mi++)
#pragma unroll
                for (int ni = 0; ni < 4; ni++)
                    acc[mi][ni] = __builtin_amdgcn_mfma_f32_16x16x32_bf16(af[mi], bf[ni], acc[mi][ni], 0, 0, 0);
        }
        __syncthreads();
    }
#pragma unroll
    for (int mi = 0; mi < 4; mi++)
#pragma unroll
        for (int ni = 0; ni < 4; ni++)
#pragma unroll
            for (int r = 0; r < 4; r++) {
                int m = rowB + mi * 16 + (lane >> 4) * 4 + r;
                int n = colB + ni * 16 + (lane & 15);
                C1[(size_t)(slot0 + m) * TWO_FFN + ct * 128 + n] = f2bf(acc[mi][ni][r]);
            }
}

// ---------- 5. swiglu: A2[slot][j] = silu(g)*u ----------
__global__ void k_swiglu(const unsigned short* __restrict__ C1, unsigned short* __restrict__ A2) {
    int gid = blockIdx.x * 256 + threadIdx.x;
    int row = gid / 352;
    int j   = (gid - row * 352) * 4;
    const unsigned short* g = C1 + (size_t)row * TWO_FFN + j;
    unsigned short o[4];
#pragma unroll
    for (int i = 0; i < 4; i++) {
        float gv = bf2f(g[i]);
        float uv = bf2f(g[i + FFN_]);
        float s = gv / (1.f + expf(-gv));
        o[i] = f2bf(s * uv);
    }
    *(uint2*)(A2 + (size_t)row * FFN_ + j) = *(const uint2*)o;
}

// ---------- 6. GEMM2 (split-K=2): A2[128,1408] @ w2bt^T -> Yp fp32 partials ----------
__global__ __launch_bounds__(256) void k_gemm2(
    const unsigned short* __restrict__ A2, const unsigned short* __restrict__ w2bt,
    const int* __restrict__ ctrl, float* __restrict__ Yp) {
    int nt = ctrl[24];
    int tileIdx = blockIdx.x;
    if (tileIdx >= nt) return;
    int e     = ctrl[32 + tileIdx];
    int slot0 = ctrl[96 + tileIdx];
    int ct    = blockIdx.y;                     // 0..7 column tiles over H
    int ks    = blockIdx.z;                     // K split 0..1, 704 each
    __shared__ unsigned short As[128 * 64];
    __shared__ unsigned short Bs[128 * 64];
    int tid = threadIdx.x, wid = tid >> 6, lane = tid & 63;

    const unsigned short* aPtr[4];
    const unsigned short* bPtr[4];
    unsigned short* lA[4];
    unsigned short* lB[4];
#pragma unroll
    for (int i = 0; i < 4; i++) {
        int c = (wid * 4 + i) * 64 + lane;
        int r = c >> 3;
        int qd = (c & 7) ^ (r & 7);
        int col8 = qd * 8;
        aPtr[i] = A2 + (size_t)(slot0 + r) * FFN_ + col8;
        bPtr[i] = w2bt + ((size_t)e * H_ + ct * 128 + r) * FFN_ + col8;
        lA[i] = As + (size_t)c * 8;
        lB[i] = Bs + (size_t)c * 8;
    }
    f32x4 acc[4][4];
#pragma unroll
    for (int mi = 0; mi < 4; mi++)
#pragma unroll
        for (int ni = 0; ni < 4; ni++) acc[mi][ni] = (f32x4){0.f, 0.f, 0.f, 0.f};
    int wm = wid & 1, wn = wid >> 1;
    int rowB = wm * 64, colB = wn * 64;
    int sw = (lane & 7) << 3;

    int kbeg = ks * (FFN_ / 2), kend = kbeg + FFN_ / 2;   // 11 steps each
    for (int k0 = kbeg; k0 < kend; k0 += 64) {
#pragma unroll
        for (int i = 0; i < 4; i++) { async16(aPtr[i] + k0, lA[i]); async16(bPtr[i] + k0, lB[i]); }
        __syncthreads();
#pragma unroll
        for (int kk = 0; kk < 64; kk += 32) {
            int kr = (kk + ((lane >> 4) << 3)) ^ sw;
            s16x8 af[4], bf[4];
#pragma unroll
            for (int mi = 0; mi < 4; mi++) af[mi] = *(const s16x8*)&As[(rowB + mi * 16 + (lane & 15)) * 64 + kr];
#pragma unroll
            for (int ni = 0; ni < 4; ni++) bf[ni] = *(const s16x8*)&Bs[(colB + ni * 16 + (lane & 15)) * 64 + kr];
#pragma unroll
            for (int mi = 0; mi < 4; mi++)
#pragma unroll
                for (int ni = 0; ni < 4; ni++)
                    acc[mi][ni] = __builtin_amdgcn_mfma_f32_16x16x32_bf16(af[mi], bf[ni], acc[mi][ni], 0, 0, 0);
        }
        __syncthreads();
    }
    float* yp = Yp + (size_t)ks * MAXSLOTS * H_;
#pragma unroll
    for (int mi = 0; mi < 4; mi++)
#pragma unroll
        for (int r = 0; r < 4; r++) {
            int m = rowB + mi * 16 + (lane >> 4) * 4 + r;
#pragma unroll
            for (int ni = 0; ni < 4; ni++) {
                int n = colB + ni * 16 + (lane & 15);
                yp[(size_t)(slot0 + m) * H_ + ct * 128 + n] = acc[mi][ni][r];
            }
        }
}

// ---------- 7. combine: out[t][h] = wA*(Yp0[sA]+Yp1[sA]) + wB*(Yp0[sB]+Yp1[sB]) ----------
__global__ void k_combine(const float* __restrict__ Yp, const int* __restrict__ slotOfTok,
                          const float* __restrict__ topkW, float* __restrict__ out) {
    int t = blockIdx.x;
    int h = threadIdx.x * 4;
    int sA = slotOfTok[2 * t], sB = slotOfTok[2 * t + 1];
    float wA = topkW[2 * t],   wB = topkW[2 * t + 1];
    const float4 a0 = *(const float4*)(Yp + (size_t)sA * H_ + h);
    const float4 a1 = *(const float4*)(Yp + ((size_t)MAXSLOTS + sA) * H_ + h);
    const float4 b0 = *(const float4*)(Yp + (size_t)sB * H_ + h);
    const float4 b1 = *(const float4*)(Yp + ((size_t)MAXSLOTS + sB) * H_ + h);
    float4 r;
    r.x = wA * (a0.x + a1.x) + wB * (b0.x + b1.x);
    r.y = wA * (a0.y + a1.y) + wB * (b0.y + b1.y);
    r.z = wA * (a0.z + a1.z) + wB * (b0.z + b1.z);
    r.w = wA * (a0.w + a1.w) + wB * (b0.w + b1.w);
    *(float4*)(out + xrow_off(t) + h) = r;
}

extern "C" void kernel_launch(void* const* d_in, const int* in_sizes, int n_in,
                              void* d_out, int out_size, void* d_ws, size_t ws_size,
                              hipStream_t stream) {
    (void)in_sizes; (void)n_in; (void)ws_size; (void)out_size;
    const float* hs = (const float*)d_in[0];
    const float* gw = (const float*)d_in[1];
    const float* w1 = (const float*)d_in[2];
    const float* w2 = (const float*)d_in[3];
    float* out = (float*)d_out;
    char* ws = (char*)d_ws;

    int*            ctrl   = (int*)ws;                                  // 1 KB
    int*            topkI  = (int*)(ws + (16u << 10));                  // 16 KB
    float*          topkW  = (float*)(ws + (48u << 10));                // 16 KB
    int*            perm   = (int*)(ws + (80u << 10));                  // 20 KB
    float*          wgt    = (float*)(ws + (112u << 10));               // 20 KB
    int*            slotOfTok = (int*)(ws + (144u << 10));              // 16 KB
    unsigned short* xb    = (unsigned short*)(ws + (1ull  << 20));      // 4 MiB
    unsigned short* w1bt  = (unsigned short*)(ws + (5ull  << 20));      // 44 MiB (dead after gemm1)
    float*          Yp    = (float*)(ws + (5ull << 20));                // 40 MiB — ALIASES w1bt
    unsigned short* w2bt  = (unsigned short*)(ws + (49ull << 20));      // 22 MiB
    unsigned short* C1    = (unsigned short*)(ws + (71ull << 20));      // 27.5 MiB
    unsigned short* A2    = (unsigned short*)(ws + (99ull << 20));      // 13.75 MiB -> end ~112.75 MiB

    hipMemsetAsync(ctrl, 0, 1024, stream);

    k_convert_gate<<<512, 256, 0, stream>>>(hs, gw, xb, topkI, topkW, ctrl);
    k_transpose_bf16<<<dim3(TWO_FFN / 32, H_ / 32, E_), dim3(32, 8), 0, stream>>>(w1, w1bt, H_, TWO_FFN);
    k_transpose_bf16<<<dim3(H_ / 32, FFN_ / 32, E_), dim3(32, 8), 0, stream>>>(w2, w2bt, FFN_, H_);
    k_routeassign<<<1, 256, 0, stream>>>(topkI, topkW, ctrl, perm, wgt, slotOfTok);
    k_gemm1<<<dim3(MAXTILES, TWO_FFN / 128), 256, 0, stream>>>(xb, w1bt, ctrl, perm, C1);
    k_swiglu<<<7040, 256, 0, stream>>>(C1, A2);
    k_gemm2<<<dim3(MAXTILES, H_ / 128, 2), 256, 0, stream>>>(A2, w2bt, ctrl, Yp);
    k_combine<<<2048, 256, 0, stream>>>(Yp, slotOfTok, topkW, out);
}

// Round 3
// 289.836 us; speedup vs baseline: 1.4759x; 1.1541x over previous
//
#include <hip/hip_runtime.h>
#include <hip/hip_bf16.h>

// Problem constants
#define S_      1024
#define B_      2
#define H_      1024
#define E_      8
#define FFN_    1408
#define TWO_FFN 2816
#define T_      2048          // B_*S_
#define MAXSLOTS 5120         // >= 39 tiles * 128
#define MAXTILES 40

typedef float  f32x4 __attribute__((ext_vector_type(4)));
typedef short  s16x8 __attribute__((ext_vector_type(8)));

// ---------- helpers ----------
__device__ __forceinline__ unsigned short f2bf(float f) {
    unsigned u = __float_as_uint(f);
    u += 0x7fffu + ((u >> 16) & 1u);          // round-to-nearest-even
    return (unsigned short)(u >> 16);
}
__device__ __forceinline__ void async16(const void* g, void* l) {
    __builtin_amdgcn_global_load_lds(
        (const __attribute__((address_space(1))) unsigned int*)(unsigned long long)g,
        (__attribute__((address_space(3))) unsigned int*)(unsigned long long)l,
        16, 0, 0);
}
__device__ __forceinline__ size_t xrow_off(int t) {
    return (size_t)(t & (S_ - 1)) * (B_ * H_) + (size_t)(t >> 10) * H_;
}

// ---------- 1. fused convert x (permute [S,B,H]->[T,H], fp32->bf16) + gate top-2 ----------
// NO global atomics (R2 post-mortem: 4096 atomicAdds on one cache line = 56 us).
__global__ void k_convert_gate(const float* __restrict__ hs, const float* __restrict__ gw,
                               unsigned short* __restrict__ xb,
                               int* __restrict__ topkI, float* __restrict__ topkW) {
    int wid = threadIdx.x >> 6, lane = threadIdx.x & 63;
    int t = blockIdx.x * 4 + wid;                 // 512 blocks -> 2048 tokens
    const float* xr = hs + xrow_off(t);
    unsigned short* xo = xb + (size_t)t * H_;
    float acc[E_];
#pragma unroll
    for (int e = 0; e < E_; e++) acc[e] = 0.f;
#pragma unroll
    for (int p = 0; p < 4; p++) {
        int h = p * 256 + lane * 4;
        const float4 v = *(const float4*)(xr + h);
        unsigned short o[4] = { f2bf(v.x), f2bf(v.y), f2bf(v.z), f2bf(v.w) };
        *(uint2*)(xo + h) = *(const uint2*)o;
#pragma unroll
        for (int e = 0; e < E_; e++) {
            const float4 g = *(const float4*)(gw + e * H_ + h);
            acc[e] += v.x * g.x + v.y * g.y + v.z * g.z + v.w * g.w;
        }
    }
#pragma unroll
    for (int e = 0; e < E_; e++)
        for (int off = 32; off > 0; off >>= 1) acc[e] += __shfl_down(acc[e], off);
    if (lane == 0) {
        float l0 = -1e30f, l1 = -1e30f; int i0 = 0, i1 = 0;
#pragma unroll
        for (int e = 0; e < E_; e++) {
            float v = acc[e];
            if (v > l0)      { l1 = l0; i1 = i0; l0 = v; i0 = e; }
            else if (v > l1) { l1 = v;  i1 = e; }
        }
        float p1 = expf(l1 - l0);                 // p0 = 1
        float w0 = 1.f / (1.f + p1);
        float w1 = 1.f - w0;
        topkI[2 * t] = i0; topkI[2 * t + 1] = i1;
        topkW[2 * t] = w0; topkW[2 * t + 1] = w1;
    }
}

// ---------- 2. transpose+convert: out[e][c][r] = bf16(in[e][r][c]), 64x64 tiles ----------
__global__ void k_transpose_bf16(const float* __restrict__ in, unsigned short* __restrict__ out,
                                 int R, int C) {
    __shared__ float tile[64][65];
    int e = blockIdx.z;
    const float* ip = in + (size_t)e * R * C;
    unsigned short* op = out + (size_t)e * R * C;
    int c0 = blockIdx.x * 64, r0 = blockIdx.y * 64;
    int tx = threadIdx.x, ty = threadIdx.y;   // 64 x 4
#pragma unroll
    for (int i = 0; i < 16; i++) {
        int r = ty + i * 4;
        tile[tx][r] = ip[(size_t)(r0 + r) * C + c0 + tx];   // tile[c][r]
    }
    __syncthreads();
#pragma unroll
    for (int i = 0; i < 16; i++) {
        int c = ty + i * 4;
        op[(size_t)(c0 + c) * R + r0 + tx] = f2bf(tile[c][tx]);  // 128B/row writes
    }
}

// ---------- 3. fused histogram + route + assign (one block) ----------
// ctrl ints: [24]=nTiles [32..95]=tileExpert [96..159]=tileSlotBase
__global__ void k_routeassign(const int* __restrict__ topkI, const float* __restrict__ topkW,
                              int* __restrict__ ctrl, int* __restrict__ perm,
                              float* __restrict__ wgt, int* __restrict__ slotOfTok) {
    __shared__ int s_wcnt[4][E_];
    __shared__ int s_base[E_];
    __shared__ int s_cur[E_];
    int tid = threadIdx.x, wid = tid >> 6, lane = tid & 63;
    // histogram in registers
    int cnt[E_];
#pragma unroll
    for (int j = 0; j < E_; j++) cnt[j] = 0;
    for (int i = tid; i < 2 * T_; i += 256) {
        int e = topkI[i];
#pragma unroll
        for (int j = 0; j < E_; j++) cnt[j] += (e == j);
    }
#pragma unroll
    for (int j = 0; j < E_; j++)
        for (int off = 32; off > 0; off >>= 1) cnt[j] += __shfl_down(cnt[j], off);
    if (lane == 0) {
#pragma unroll
        for (int j = 0; j < E_; j++) s_wcnt[wid][j] = cnt[j];
    }
    __syncthreads();
    if (tid == 0) {
        int b = 0, nt = 0;
        for (int e = 0; e < E_; e++) {
            int n = s_wcnt[0][e] + s_wcnt[1][e] + s_wcnt[2][e] + s_wcnt[3][e];
            s_base[e] = b;
            int ntile = (n + 127) >> 7;
            for (int ti = 0; ti < ntile; ti++) { ctrl[32 + nt] = e; ctrl[96 + nt] = b + ti * 128; nt++; }
            b += ntile * 128;
        }
        ctrl[24] = nt;
#pragma unroll
        for (int e = 0; e < E_; e++) s_cur[e] = 0;
    }
    __syncthreads();
    for (int s = tid; s < MAXSLOTS; s += 256) { perm[s] = 0; wgt[s] = 0.f; }
    __syncthreads();
    for (int t = tid; t < T_; t += 256) {
#pragma unroll
        for (int k = 0; k < 2; k++) {
            int e = topkI[2 * t + k];
            int pos = atomicAdd(&s_cur[e], 1);   // LDS atomic, 8 counters, cheap
            int slot = s_base[e] + pos;
            perm[slot] = t;
            wgt[slot]  = topkW[2 * t + k];
            slotOfTok[2 * t + k] = slot;
        }
    }
}

// ---------- 4. GEMM1 + fused swiglu epilogue ----------
// Block computes C[128 slots][64 gate cols + 64 matching up cols]; wn=1 waves
// pass their up-half through LDS; wn=0 waves emit A2 = silu(g)*u directly.
__global__ __launch_bounds__(256) void k_gemm1(
    const unsigned short* __restrict__ xb, const unsigned short* __restrict__ w1bt,
    const int* __restrict__ ctrl, const int* __restrict__ perm,
    unsigned short* __restrict__ A2) {
    int nt = ctrl[24];
    int tileIdx = blockIdx.x;
    if (tileIdx >= nt) return;
    int e     = ctrl[32 + tileIdx];
    int slot0 = ctrl[96 + tileIdx];
    int ct    = blockIdx.y;                     // 0..21: gate cols ct*64.., up cols 1408+ct*64..
    __shared__ __align__(16) unsigned short smem[2 * 128 * 64];   // As | Bs, reused as fp32 upLds
    unsigned short* As = smem;
    unsigned short* Bs = smem + 128 * 64;
    int tid = threadIdx.x, wid = tid >> 6, lane = tid & 63;

    const unsigned short* aPtr[4];
    const unsigned short* bPtr[4];
    unsigned short* lA[4];
    unsigned short* lB[4];
#pragma unroll
    for (int i = 0; i < 4; i++) {
        int c = (wid * 4 + i) * 64 + lane;      // chunk id 0..1023
        int r = c >> 3;
        int qd = (c & 7) ^ (r & 7);             // XOR swizzle
        int col8 = qd * 8;
        int tok = perm[slot0 + r];
        int gr = (r < 64) ? (ct * 64 + r) : (FFN_ + ct * 64 + (r - 64));  // gate/up rows
        aPtr[i] = xb + (size_t)tok * H_ + col8;
        bPtr[i] = w1bt + ((size_t)e * TWO_FFN + gr) * H_ + col8;
        lA[i] = As + (size_t)c * 8;
        lB[i] = Bs + (size_t)c * 8;
    }
    f32x4 acc[4][4];
#pragma unroll
    for (int mi = 0; mi < 4; mi++)
#pragma unroll
        for (int ni = 0; ni < 4; ni++) acc[mi][ni] = (f32x4){0.f, 0.f, 0.f, 0.f};
    int wm = wid & 1, wn = wid >> 1;
    int rowB = wm * 64, colB = wn * 64;
    int sw = (lane & 7) << 3;

    for (int k0 = 0; k0 < H_; k0 += 64) {
#pragma unroll
        for (int i = 0; i < 4; i++) { async16(aPtr[i] + k0, lA[i]); async16(bPtr[i] + k0, lB[i]); }
        __syncthreads();
#pragma unroll
        for (int kk = 0; kk < 64; kk += 32) {
            int kr = (kk + ((lane >> 4) << 3)) ^ sw;
            s16x8 af[4], bf[4];
#pragma unroll
            for (int mi = 0; mi < 4; mi++) af[mi] = *(const s16x8*)&As[(rowB + mi * 16 + (lane & 15)) * 64 + kr];
#pragma unroll
            for (int ni = 0; ni < 4; ni++) bf[ni] = *(const s16x8*)&Bs[(colB + ni * 16 + (lane & 15)) * 64 + kr];
#pragma unroll
            for (int mi = 0; mi < 4; mi++)
#pragma unroll
                for (int ni = 0; ni < 4; ni++)
                    acc[mi][ni] = __builtin_amdgcn_mfma_f32_16x16x32_bf16(af[mi], bf[ni], acc[mi][ni], 0, 0, 0);
        }
        __syncthreads();
    }
    // ---- fused swiglu epilogue ----
    float* upLds = (float*)smem;                // 128 x 64 fp32 = 32 KB
    if (wn == 1) {
#pragma unroll
        for (int mi = 0; mi < 4; mi++)
#pragma unroll
            for (int ni = 0; ni < 4; ni++)
#pragma unroll
                for (int r = 0; r < 4; r++) {
                    int m = rowB + mi * 16 + (lane >> 4) * 4 + r;
                    int u = ni * 16 + (lane & 15);
                    upLds[m * 64 + u] = acc[mi][ni][r];
                }
    }
    __syncthreads();
    if (wn == 0) {
#pragma unroll
        for (int mi = 0; mi < 4; mi++)
#pragma unroll
            for (int r = 0; r < 4; r++) {
                int m = rowB + mi * 16 + (lane >> 4) * 4 + r;
                unsigned short* arow = A2 + (size_t)(slot0 + m) * FFN_ + ct * 64;
#pragma unroll
                for (int ni = 0; ni < 4; ni++) {
                    int gl = ni * 16 + (lane & 15);
                    float g = acc[mi][ni][r];
                    float u = upLds[m * 64 + gl];
                    float s = g / (1.f + expf(-g));
                    arow[gl] = f2bf(s * u);
                }
            }
    }
}

// ---------- 5. GEMM2 (split-K=2): A2[128,1408] @ w2bt^T -> Yp fp32 partials ----------
__global__ __launch_bounds__(256) void k_gemm2(
    const unsigned short* __restrict__ A2, const unsigned short* __restrict__ w2bt,
    const int* __restrict__ ctrl, float* __restrict__ Yp) {
    int nt = ctrl[24];
    int tileIdx = blockIdx.x;
    if (tileIdx >= nt) return;
    int e     = ctrl[32 + tileIdx];
    int slot0 = ctrl[96 + tileIdx];
    int ct    = blockIdx.y;                     // 0..7 column tiles over H
    int ks    = blockIdx.z;                     // K split 0..1, 704 each
    __shared__ __align__(16) unsigned short As[128 * 64];
    __shared__ __align__(16) unsigned short Bs[128 * 64];
    int tid = threadIdx.x, wid = tid >> 6, lane = tid & 63;

    const unsigned short* aPtr[4];
    const unsigned short* bPtr[4];
    unsigned short* lA[4];
    unsigned short* lB[4];
#pragma unroll
    for (int i = 0; i < 4; i++) {
        int c = (wid * 4 + i) * 64 + lane;
        int r = c >> 3;
        int qd = (c & 7) ^ (r & 7);
        int col8 = qd * 8;
        aPtr[i] = A2 + (size_t)(slot0 + r) * FFN_ + col8;
        bPtr[i] = w2bt + ((size_t)e * H_ + ct * 128 + r) * FFN_ + col8;
        lA[i] = As + (size_t)c * 8;
        lB[i] = Bs + (size_t)c * 8;
    }
    f32x4 acc[4][4];
#pragma unroll
    for (int mi = 0; mi < 4; mi++)
#pragma unroll
        for (int ni = 0; ni < 4; ni++) acc[mi][ni] = (f32x4){0.f, 0.f, 0.f, 0.f};
    int wm = wid & 1, wn = wid >> 1;
    int rowB = wm * 64, colB = wn * 64;
    int sw = (lane & 7) << 3;

    int kbeg = ks * (FFN_ / 2), kend = kbeg + FFN_ / 2;   // 11 steps each
    for (int k0 = kbeg; k0 < kend; k0 += 64) {
#pragma unroll
        for (int i = 0; i < 4; i++) { async16(aPtr[i] + k0, lA[i]); async16(bPtr[i] + k0, lB[i]); }
        __syncthreads();
#pragma unroll
        for (int kk = 0; kk < 64; kk += 32) {
            int kr = (kk + ((lane >> 4) << 3)) ^ sw;
            s16x8 af[4], bf[4];
#pragma unroll
            for (int mi = 0; mi < 4; mi++) af[mi] = *(const s16x8*)&As[(rowB + mi * 16 + (lane & 15)) * 64 + kr];
#pragma unroll
            for (int ni = 0; ni < 4; ni++) bf[ni] = *(const s16x8*)&Bs[(colB + ni * 16 + (lane & 15)) * 64 + kr];
#pragma unroll
            for (int mi = 0; mi < 4; mi++)
#pragma unroll
                for (int ni = 0; ni < 4; ni++)
                    acc[mi][ni] = __builtin_amdgcn_mfma_f32_16x16x32_bf16(af[mi], bf[ni], acc[mi][ni], 0, 0, 0);
        }
        __syncthreads();
    }
    float* yp = Yp + (size_t)ks * MAXSLOTS * H_;
#pragma unroll
    for (int mi = 0; mi < 4; mi++)
#pragma unroll
        for (int r = 0; r < 4; r++) {
            int m = rowB + mi * 16 + (lane >> 4) * 4 + r;
#pragma unroll
            for (int ni = 0; ni < 4; ni++) {
                int n = colB + ni * 16 + (lane & 15);
                yp[(size_t)(slot0 + m) * H_ + ct * 128 + n] = acc[mi][ni][r];
            }
        }
}

// ---------- 6. combine ----------
__global__ void k_combine(const float* __restrict__ Yp, const int* __restrict__ slotOfTok,
                          const float* __restrict__ topkW, float* __restrict__ out) {
    int t = blockIdx.x;
    int h = threadIdx.x * 4;
    int sA = slotOfTok[2 * t], sB = slotOfTok[2 * t + 1];
    float wA = topkW[2 * t],   wB = topkW[2 * t + 1];
    const float4 a0 = *(const float4*)(Yp + (size_t)sA * H_ + h);
    const float4 a1 = *(const float4*)(Yp + ((size_t)MAXSLOTS + sA) * H_ + h);
    const float4 b0 = *(const float4*)(Yp + (size_t)sB * H_ + h);
    const float4 b1 = *(const float4*)(Yp + ((size_t)MAXSLOTS + sB) * H_ + h);
    float4 r;
    r.x = wA * (a0.x + a1.x) + wB * (b0.x + b1.x);
    r.y = wA * (a0.y + a1.y) + wB * (b0.y + b1.y);
    r.z = wA * (a0.z + a1.z) + wB * (b0.z + b1.z);
    r.w = wA * (a0.w + a1.w) + wB * (b0.w + b1.w);
    *(float4*)(out + xrow_off(t) + h) = r;
}

extern "C" void kernel_launch(void* const* d_in, const int* in_sizes, int n_in,
                              void* d_out, int out_size, void* d_ws, size_t ws_size,
                              hipStream_t stream) {
    (void)in_sizes; (void)n_in; (void)ws_size; (void)out_size;
    const float* hs = (const float*)d_in[0];
    const float* gw = (const float*)d_in[1];
    const float* w1 = (const float*)d_in[2];
    const float* w2 = (const float*)d_in[3];
    float* out = (float*)d_out;
    char* ws = (char*)d_ws;

    int*            ctrl   = (int*)ws;                                  // 1 KB
    int*            topkI  = (int*)(ws + (16u << 10));                  // 16 KB
    float*          topkW  = (float*)(ws + (48u << 10));                // 16 KB
    int*            perm   = (int*)(ws + (80u << 10));                  // 20 KB
    float*          wgt    = (float*)(ws + (112u << 10));               // 20 KB
    int*            slotOfTok = (int*)(ws + (144u << 10));              // 16 KB
    unsigned short* xb    = (unsigned short*)(ws + (1ull  << 20));      // 4 MiB
    unsigned short* w1bt  = (unsigned short*)(ws + (5ull  << 20));      // 44 MiB (dead after gemm1)
    float*          Yp    = (float*)(ws + (5ull << 20));                // 40 MiB — ALIASES w1bt
    unsigned short* w2bt  = (unsigned short*)(ws + (49ull << 20));      // 22 MiB
    unsigned short* A2    = (unsigned short*)(ws + (71ull << 20));      // 13.75 MiB -> end ~85 MiB

    k_convert_gate<<<512, 256, 0, stream>>>(hs, gw, xb, topkI, topkW);
    k_transpose_bf16<<<dim3(TWO_FFN / 64, H_ / 64, E_), dim3(64, 4), 0, stream>>>(w1, w1bt, H_, TWO_FFN);
    k_transpose_bf16<<<dim3(H_ / 64, FFN_ / 64, E_), dim3(64, 4), 0, stream>>>(w2, w2bt, FFN_, H_);
    k_routeassign<<<1, 256, 0, stream>>>(topkI, topkW, ctrl, perm, wgt, slotOfTok);
    k_gemm1<<<dim3(MAXTILES, FFN_ / 64), 256, 0, stream>>>(xb, w1bt, ctrl, perm, A2);
    k_gemm2<<<dim3(MAXTILES, H_ / 128, 2), 256, 0, stream>>>(A2, w2bt, ctrl, Yp);
    k_combine<<<2048, 256, 0, stream>>>(Yp, slotOfTok, topkW, out);
}

// Round 4
// 281.736 us; speedup vs baseline: 1.5184x; 1.0287x over previous
//
#include <hip/hip_runtime.h>
#include <hip/hip_bf16.h>

// Problem constants
#define S_      1024
#define B_      2
#define H_      1024
#define E_      8
#define FFN_    1408
#define TWO_FFN 2816
#define T_      2048          // B_*S_
#define MAXSLOTS 5120         // sum slots <= 4096 + 8*127 = 5112
// prep kernel block partition
#define NB_T1   (44 * 16 * 8)   // w1 transpose: 5632 blocks
#define NB_T2   (16 * 22 * 8)   // w2 transpose: 2816 blocks
#define NB_CONV 512             // convert+gate
#define NB_PREP (NB_T1 + NB_T2 + NB_CONV)

typedef float  f32x4 __attribute__((ext_vector_type(4)));
typedef short  s16x8 __attribute__((ext_vector_type(8)));

// ---------- helpers ----------
__device__ __forceinline__ unsigned short f2bf(float f) {
    unsigned u = __float_as_uint(f);
    u += 0x7fffu + ((u >> 16) & 1u);          // round-to-nearest-even
    return (unsigned short)(u >> 16);
}
__device__ __forceinline__ void async16(const void* g, void* l) {
    __builtin_amdgcn_global_load_lds(
        (const __attribute__((address_space(1))) unsigned int*)(unsigned long long)g,
        (__attribute__((address_space(3))) unsigned int*)(unsigned long long)l,
        16, 0, 0);
}
__device__ __forceinline__ size_t xrow_off(int t) {
    return (size_t)(t & (S_ - 1)) * (B_ * H_) + (size_t)(t >> 10) * H_;
}

// ---------- 1. merged prep: w1 transpose | w2 transpose | convert+gate ----------
// transpose: out[e][c][r] = bf16(in[e][r][c]), 64x64 tiles
__device__ __forceinline__ void transpose_body(const float* __restrict__ ip,
                                               unsigned short* __restrict__ op,
                                               int R, int C, int r0, int c0,
                                               float (*tile)[65], int tid) {
    int tx = tid & 63, ty = tid >> 6;   // 64 x 4
#pragma unroll
    for (int i = 0; i < 16; i++) {
        int r = ty + i * 4;
        tile[tx][r] = ip[(size_t)(r0 + r) * C + c0 + tx];
    }
    __syncthreads();
#pragma unroll
    for (int i = 0; i < 16; i++) {
        int c = ty + i * 4;
        op[(size_t)(c0 + c) * R + r0 + tx] = f2bf(tile[c][tx]);  // 128B/row writes
    }
}

__global__ void k_prep(const float* __restrict__ hs, const float* __restrict__ gw,
                       const float* __restrict__ w1, const float* __restrict__ w2,
                       unsigned short* __restrict__ xb,
                       unsigned short* __restrict__ w1bt, unsigned short* __restrict__ w2bt,
                       int* __restrict__ topkI, float* __restrict__ topkW) {
    __shared__ float tile[64][65];
    int bx = blockIdx.x, tid = threadIdx.x;
    if (bx < NB_T1) {
        // w1: R=1024 rows(k), C=2816 cols(n); ctiles=44, rtiles=16
        int e = bx / (44 * 16), rem = bx % (44 * 16);
        int c0 = (rem % 44) * 64, r0 = (rem / 44) * 64;
        transpose_body(w1 + (size_t)e * (H_ * TWO_FFN), w1bt + (size_t)e * (H_ * TWO_FFN),
                       H_, TWO_FFN, r0, c0, tile, tid);
        return;
    }
    if (bx < NB_T1 + NB_T2) {
        // w2: R=1408, C=1024; ctiles=16, rtiles=22
        int b2 = bx - NB_T1;
        int e = b2 / (16 * 22), rem = b2 % (16 * 22);
        int c0 = (rem % 16) * 64, r0 = (rem / 16) * 64;
        transpose_body(w2 + (size_t)e * (FFN_ * H_), w2bt + (size_t)e * (FFN_ * H_),
                       FFN_, H_, r0, c0, tile, tid);
        return;
    }
    // convert + gate (no global atomics)
    int cb = bx - (NB_T1 + NB_T2);
    int wid = tid >> 6, lane = tid & 63;
    int t = cb * 4 + wid;
    const float* xr = hs + xrow_off(t);
    unsigned short* xo = xb + (size_t)t * H_;
    float acc[E_];
#pragma unroll
    for (int e = 0; e < E_; e++) acc[e] = 0.f;
#pragma unroll
    for (int p = 0; p < 4; p++) {
        int h = p * 256 + lane * 4;
        const float4 v = *(const float4*)(xr + h);
        unsigned short o[4] = { f2bf(v.x), f2bf(v.y), f2bf(v.z), f2bf(v.w) };
        *(uint2*)(xo + h) = *(const uint2*)o;
#pragma unroll
        for (int e = 0; e < E_; e++) {
            const float4 g = *(const float4*)(gw + e * H_ + h);
            acc[e] += v.x * g.x + v.y * g.y + v.z * g.z + v.w * g.w;
        }
    }
#pragma unroll
    for (int e = 0; e < E_; e++)
        for (int off = 32; off > 0; off >>= 1) acc[e] += __shfl_down(acc[e], off);
    if (lane == 0) {
        float l0 = -1e30f, l1 = -1e30f; int i0 = 0, i1 = 0;
#pragma unroll
        for (int e = 0; e < E_; e++) {
            float v = acc[e];
            if (v > l0)      { l1 = l0; i1 = i0; l0 = v; i0 = e; }
            else if (v > l1) { l1 = v;  i1 = e; }
        }
        float p1 = expf(l1 - l0);                 // p0 = 1
        float w0 = 1.f / (1.f + p1);
        float w1s = 1.f - w0;
        topkI[2 * t] = i0; topkI[2 * t + 1] = i1;
        topkW[2 * t] = w0; topkW[2 * t + 1] = w1s;
    }
}

// ---------- 2. fused histogram + route + assign (one block) ----------
// ctrl ints: [40+e]=ntile(e)  [48+e]=slotBase(e)
__global__ void k_routeassign(const int* __restrict__ topkI, const float* __restrict__ topkW,
                              int* __restrict__ ctrl, int* __restrict__ perm,
                              float* __restrict__ wgt, int* __restrict__ slotOfTok) {
    __shared__ int s_wcnt[4][E_];
    __shared__ int s_base[E_];
    __shared__ int s_cur[E_];
    int tid = threadIdx.x, wid = tid >> 6, lane = tid & 63;
    int cnt[E_];
#pragma unroll
    for (int j = 0; j < E_; j++) cnt[j] = 0;
    for (int i = tid; i < 2 * T_; i += 256) {
        int e = topkI[i];
#pragma unroll
        for (int j = 0; j < E_; j++) cnt[j] += (e == j);
    }
#pragma unroll
    for (int j = 0; j < E_; j++)
        for (int off = 32; off > 0; off >>= 1) cnt[j] += __shfl_down(cnt[j], off);
    if (lane == 0) {
#pragma unroll
        for (int j = 0; j < E_; j++) s_wcnt[wid][j] = cnt[j];
    }
    __syncthreads();
    if (tid == 0) {
        int b = 0;
        for (int e = 0; e < E_; e++) {
            int n = s_wcnt[0][e] + s_wcnt[1][e] + s_wcnt[2][e] + s_wcnt[3][e];
            int ntile = (n + 127) >> 7;
            s_base[e] = b;
            ctrl[40 + e] = ntile;
            ctrl[48 + e] = b;
            b += ntile * 128;
        }
#pragma unroll
        for (int e = 0; e < E_; e++) s_cur[e] = 0;
    }
    __syncthreads();
    for (int s = tid; s < MAXSLOTS; s += 256) { perm[s] = 0; wgt[s] = 0.f; }
    __syncthreads();
    for (int t = tid; t < T_; t += 256) {
#pragma unroll
        for (int k = 0; k < 2; k++) {
            int e = topkI[2 * t + k];
            int pos = atomicAdd(&s_cur[e], 1);   // LDS atomic
            int slot = s_base[e] + pos;
            perm[slot] = t;
            wgt[slot]  = topkW[2 * t + k];
            slotOfTok[2 * t + k] = slot;
        }
    }
}

// ---------- 3. GEMM1 + fused swiglu epilogue ----------
// Grid: x = e + 8*ct (176), y = tile-in-expert (16). Same (e,ct) => same id mod 8
// => same XCD => the shared 128x1024 B-slice is fetched into one L2 (R3: 56MB re-fetch).
__global__ __launch_bounds__(256) void k_gemm1(
    const unsigned short* __restrict__ xb, const unsigned short* __restrict__ w1bt,
    const int* __restrict__ ctrl, const int* __restrict__ perm,
    unsigned short* __restrict__ A2) {
    int e  = blockIdx.x & 7;
    int ct = blockIdx.x >> 3;                   // 0..21
    int ti = blockIdx.y;
    if (ti >= ctrl[40 + e]) return;
    int slot0 = ctrl[48 + e] + ti * 128;
    __shared__ __align__(16) unsigned short smem[2 * 128 * 64];   // As | Bs, reused as fp32 upLds
    unsigned short* As = smem;
    unsigned short* Bs = smem + 128 * 64;
    int tid = threadIdx.x, wid = tid >> 6, lane = tid & 63;

    const unsigned short* aPtr[4];
    const unsigned short* bPtr[4];
    unsigned short* lA[4];
    unsigned short* lB[4];
#pragma unroll
    for (int i = 0; i < 4; i++) {
        int c = (wid * 4 + i) * 64 + lane;      // chunk id 0..1023
        int r = c >> 3;
        int qd = (c & 7) ^ (r & 7);             // XOR swizzle
        int col8 = qd * 8;
        int tok = perm[slot0 + r];
        int gr = (r < 64) ? (ct * 64 + r) : (FFN_ + ct * 64 + (r - 64));  // gate/up rows
        aPtr[i] = xb + (size_t)tok * H_ + col8;
        bPtr[i] = w1bt + ((size_t)e * TWO_FFN + gr) * H_ + col8;
        lA[i] = As + (size_t)c * 8;
        lB[i] = Bs + (size_t)c * 8;
    }
    f32x4 acc[4][4];
#pragma unroll
    for (int mi = 0; mi < 4; mi++)
#pragma unroll
        for (int ni = 0; ni < 4; ni++) acc[mi][ni] = (f32x4){0.f, 0.f, 0.f, 0.f};
    int wm = wid & 1, wn = wid >> 1;
    int rowB = wm * 64, colB = wn * 64;
    int sw = (lane & 7) << 3;

    for (int k0 = 0; k0 < H_; k0 += 64) {
#pragma unroll
        for (int i = 0; i < 4; i++) { async16(aPtr[i] + k0, lA[i]); async16(bPtr[i] + k0, lB[i]); }
        __syncthreads();
#pragma unroll
        for (int kk = 0; kk < 64; kk += 32) {
            int kr = (kk + ((lane >> 4) << 3)) ^ sw;
            s16x8 af[4], bf[4];
#pragma unroll
            for (int mi = 0; mi < 4; mi++) af[mi] = *(const s16x8*)&As[(rowB + mi * 16 + (lane & 15)) * 64 + kr];
#pragma unroll
            for (int ni = 0; ni < 4; ni++) bf[ni] = *(const s16x8*)&Bs[(colB + ni * 16 + (lane & 15)) * 64 + kr];
#pragma unroll
            for (int mi = 0; mi < 4; mi++)
#pragma unroll
                for (int ni = 0; ni < 4; ni++)
                    acc[mi][ni] = __builtin_amdgcn_mfma_f32_16x16x32_bf16(af[mi], bf[ni], acc[mi][ni], 0, 0, 0);
        }
        __syncthreads();
    }
    // ---- fused swiglu epilogue ----
    float* upLds = (float*)smem;                // 128 x 64 fp32 = 32 KB
    if (wn == 1) {
#pragma unroll
        for (int mi = 0; mi < 4; mi++)
#pragma unroll
            for (int ni = 0; ni < 4; ni++)
#pragma unroll
                for (int r = 0; r < 4; r++) {
                    int m = rowB + mi * 16 + (lane >> 4) * 4 + r;
                    int u = ni * 16 + (lane & 15);
                    upLds[m * 64 + u] = acc[mi][ni][r];
                }
    }
    __syncthreads();
    if (wn == 0) {
#pragma unroll
        for (int mi = 0; mi < 4; mi++)
#pragma unroll
            for (int r = 0; r < 4; r++) {
                int m = rowB + mi * 16 + (lane >> 4) * 4 + r;
                unsigned short* arow = A2 + (size_t)(slot0 + m) * FFN_ + ct * 64;
#pragma unroll
                for (int ni = 0; ni < 4; ni++) {
                    int gl = ni * 16 + (lane & 15);
                    float g = acc[mi][ni][r];
                    float u = upLds[m * 64 + gl];
                    float s = g / (1.f + expf(-g));
                    arow[gl] = f2bf(s * u);
                }
            }
    }
}

// ---------- 4. GEMM2 (split-K=2): A2[128,1408] @ w2bt^T -> Yp fp32 partials ----------
// Grid: x = e + 8*ct (64), y = tile (16), z = ks (2). y/z strides mod 8 == 0 => XCD co-location.
__global__ __launch_bounds__(256) void k_gemm2(
    const unsigned short* __restrict__ A2, const unsigned short* __restrict__ w2bt,
    const int* __restrict__ ctrl, float* __restrict__ Yp) {
    int e  = blockIdx.x & 7;
    int ct = blockIdx.x >> 3;                   // 0..7
    int ti = blockIdx.y;
    if (ti >= ctrl[40 + e]) return;
    int slot0 = ctrl[48 + e] + ti * 128;
    int ks    = blockIdx.z;
    __shared__ __align__(16) unsigned short As[128 * 64];
    __shared__ __align__(16) unsigned short Bs[128 * 64];
    int tid = threadIdx.x, wid = tid >> 6, lane = tid & 63;

    const unsigned short* aPtr[4];
    const unsigned short* bPtr[4];
    unsigned short* lA[4];
    unsigned short* lB[4];
#pragma unroll
    for (int i = 0; i < 4; i++) {
        int c = (wid * 4 + i) * 64 + lane;
        int r = c >> 3;
        int qd = (c & 7) ^ (r & 7);
        int col8 = qd * 8;
        aPtr[i] = A2 + (size_t)(slot0 + r) * FFN_ + col8;
        bPtr[i] = w2bt + ((size_t)e * H_ + ct * 128 + r) * FFN_ + col8;
        lA[i] = As + (size_t)c * 8;
        lB[i] = Bs + (size_t)c * 8;
    }
    f32x4 acc[4][4];
#pragma unroll
    for (int mi = 0; mi < 4; mi++)
#pragma unroll
        for (int ni = 0; ni < 4; ni++) acc[mi][ni] = (f32x4){0.f, 0.f, 0.f, 0.f};
    int wm = wid & 1, wn = wid >> 1;
    int rowB = wm * 64, colB = wn * 64;
    int sw = (lane & 7) << 3;

    int kbeg = ks * (FFN_ / 2), kend = kbeg + FFN_ / 2;   // 11 steps each
    for (int k0 = kbeg; k0 < kend; k0 += 64) {
#pragma unroll
        for (int i = 0; i < 4; i++) { async16(aPtr[i] + k0, lA[i]); async16(bPtr[i] + k0, lB[i]); }
        __syncthreads();
#pragma unroll
        for (int kk = 0; kk < 64; kk += 32) {
            int kr = (kk + ((lane >> 4) << 3)) ^ sw;
            s16x8 af[4], bf[4];
#pragma unroll
            for (int mi = 0; mi < 4; mi++) af[mi] = *(const s16x8*)&As[(rowB + mi * 16 + (lane & 15)) * 64 + kr];
#pragma unroll
            for (int ni = 0; ni < 4; ni++) bf[ni] = *(const s16x8*)&Bs[(colB + ni * 16 + (lane & 15)) * 64 + kr];
#pragma unroll
            for (int mi = 0; mi < 4; mi++)
#pragma unroll
                for (int ni = 0; ni < 4; ni++)
                    acc[mi][ni] = __builtin_amdgcn_mfma_f32_16x16x32_bf16(af[mi], bf[ni], acc[mi][ni], 0, 0, 0);
        }
        __syncthreads();
    }
    float* yp = Yp + (size_t)ks * MAXSLOTS * H_;
#pragma unroll
    for (int mi = 0; mi < 4; mi++)
#pragma unroll
        for (int r = 0; r < 4; r++) {
            int m = rowB + mi * 16 + (lane >> 4) * 4 + r;
#pragma unroll
            for (int ni = 0; ni < 4; ni++) {
                int n = colB + ni * 16 + (lane & 15);
                yp[(size_t)(slot0 + m) * H_ + ct * 128 + n] = acc[mi][ni][r];
            }
        }
}

// ---------- 5. combine ----------
__global__ void k_combine(const float* __restrict__ Yp, const int* __restrict__ slotOfTok,
                          const float* __restrict__ topkW, float* __restrict__ out) {
    int t = blockIdx.x;
    int h = threadIdx.x * 4;
    int sA = slotOfTok[2 * t], sB = slotOfTok[2 * t + 1];
    float wA = topkW[2 * t],   wB = topkW[2 * t + 1];
    const float4 a0 = *(const float4*)(Yp + (size_t)sA * H_ + h);
    const float4 a1 = *(const float4*)(Yp + ((size_t)MAXSLOTS + sA) * H_ + h);
    const float4 b0 = *(const float4*)(Yp + (size_t)sB * H_ + h);
    const float4 b1 = *(const float4*)(Yp + ((size_t)MAXSLOTS + sB) * H_ + h);
    float4 r;
    r.x = wA * (a0.x + a1.x) + wB * (b0.x + b1.x);
    r.y = wA * (a0.y + a1.y) + wB * (b0.y + b1.y);
    r.z = wA * (a0.z + a1.z) + wB * (b0.z + b1.z);
    r.w = wA * (a0.w + a1.w) + wB * (b0.w + b1.w);
    *(float4*)(out + xrow_off(t) + h) = r;
}

extern "C" void kernel_launch(void* const* d_in, const int* in_sizes, int n_in,
                              void* d_out, int out_size, void* d_ws, size_t ws_size,
                              hipStream_t stream) {
    (void)in_sizes; (void)n_in; (void)ws_size; (void)out_size;
    const float* hs = (const float*)d_in[0];
    const float* gw = (const float*)d_in[1];
    const float* w1 = (const float*)d_in[2];
    const float* w2 = (const float*)d_in[3];
    float* out = (float*)d_out;
    char* ws = (char*)d_ws;

    int*            ctrl   = (int*)ws;                                  // 1 KB
    int*            topkI  = (int*)(ws + (16u << 10));                  // 16 KB
    float*          topkW  = (float*)(ws + (48u << 10));                // 16 KB
    int*            perm   = (int*)(ws + (80u << 10));                  // 20 KB
    float*          wgt    = (float*)(ws + (112u << 10));               // 20 KB
    int*            slotOfTok = (int*)(ws + (144u << 10));              // 16 KB
    unsigned short* xb    = (unsigned short*)(ws + (1ull  << 20));      // 4 MiB
    unsigned short* w1bt  = (unsigned short*)(ws + (5ull  << 20));      // 44 MiB (dead after gemm1)
    float*          Yp    = (float*)(ws + (5ull << 20));                // 40 MiB — ALIASES w1bt
    unsigned short* w2bt  = (unsigned short*)(ws + (49ull << 20));      // 22 MiB
    unsigned short* A2    = (unsigned short*)(ws + (71ull << 20));      // 13.75 MiB -> end ~85 MiB

    k_prep<<<NB_PREP, 256, 0, stream>>>(hs, gw, w1, w2, xb, w1bt, w2bt, topkI, topkW);
    k_routeassign<<<1, 256, 0, stream>>>(topkI, topkW, ctrl, perm, wgt, slotOfTok);
    k_gemm1<<<dim3(8 * (FFN_ / 64), 16), 256, 0, stream>>>(xb, w1bt, ctrl, perm, A2);
    k_gemm2<<<dim3(8 * (H_ / 128), 16, 2), 256, 0, stream>>>(A2, w2bt, ctrl, Yp);
    k_combine<<<2048, 256, 0, stream>>>(Yp, slotOfTok, topkW, out);
}

// Round 5
// 274.776 us; speedup vs baseline: 1.5568x; 1.0253x over previous
//
#include <hip/hip_runtime.h>
#include <hip/hip_bf16.h>

// Problem constants
#define S_      1024
#define B_      2
#define H_      1024
#define E_      8
#define FFN_    1408
#define TWO_FFN 2816
#define T_      2048          // B_*S_
#define MAXSLOTS 5120
// prep kernel block partition
#define NB_T1   (44 * 16 * 8)   // w1 transpose: 5632 blocks
#define NB_T2   (16 * 22 * 8)   // w2 transpose: 2816 blocks
#define NB_CONV 512             // convert+gate
#define NB_PREP (NB_T1 + NB_T2 + NB_CONV)

typedef float  f32x4 __attribute__((ext_vector_type(4)));
typedef short  s16x8 __attribute__((ext_vector_type(8)));

// ---------- helpers ----------
__device__ __forceinline__ unsigned short f2bf(float f) {
    unsigned u = __float_as_uint(f);
    u += 0x7fffu + ((u >> 16) & 1u);          // round-to-nearest-even
    return (unsigned short)(u >> 16);
}
__device__ __forceinline__ void async16(const void* g, void* l) {
    __builtin_amdgcn_global_load_lds(
        (const __attribute__((address_space(1))) unsigned int*)(unsigned long long)g,
        (__attribute__((address_space(3))) unsigned int*)(unsigned long long)l,
        16, 0, 0);
}
__device__ __forceinline__ size_t xrow_off(int t) {
    return (size_t)(t & (S_ - 1)) * (B_ * H_) + (size_t)(t >> 10) * H_;
}

// ---------- 1. merged prep: w1 transpose | w2 transpose | convert+gate ----------
// Wide 64x64 transpose: float4 loads -> LDS[c][r] (pad 65: 2-way = free) -> 16B bf16 stores.
__device__ __forceinline__ void transpose_body(const float* __restrict__ ip,
                                               unsigned short* __restrict__ op,
                                               int R, int C, int r0, int c0,
                                               float (*lds)[65], int tid) {
    int q = tid & 15, rr = tid >> 4;          // 16 threads cover one row of 64
#pragma unroll
    for (int i = 0; i < 4; i++) {
        int r = rr + 16 * i;
        const float4 v = *(const float4*)(ip + (size_t)(r0 + r) * C + c0 + q * 4);
        lds[q * 4 + 0][r] = v.x;
        lds[q * 4 + 1][r] = v.y;
        lds[q * 4 + 2][r] = v.z;
        lds[q * 4 + 3][r] = v.w;
    }
    __syncthreads();
    int oq = tid & 7, cc = tid >> 3;          // 8 threads cover one out-row of 64
#pragma unroll
    for (int i = 0; i < 2; i++) {
        int c = cc + 32 * i;
        const float* row = &lds[c][oq * 8];
        unsigned short o[8];
#pragma unroll
        for (int j = 0; j < 8; j++) o[j] = f2bf(row[j]);
        *(uint4*)(op + (size_t)(c0 + c) * R + r0 + oq * 8) = *(const uint4*)o;
    }
}

__global__ void k_prep(const float* __restrict__ hs, const float* __restrict__ gw,
                       const float* __restrict__ w1, const float* __restrict__ w2,
                       unsigned short* __restrict__ xb,
                       unsigned short* __restrict__ w1bt, unsigned short* __restrict__ w2bt,
                       int* __restrict__ topkI, float* __restrict__ topkW) {
    __shared__ float tile[64][65];
    int bx = blockIdx.x, tid = threadIdx.x;
    if (bx < NB_T1) {
        // w1: R=1024 rows(k), C=2816 cols(n); ctiles=44, rtiles=16
        int e = bx / (44 * 16), rem = bx % (44 * 16);
        int c0 = (rem % 44) * 64, r0 = (rem / 44) * 64;
        transpose_body(w1 + (size_t)e * (H_ * TWO_FFN), w1bt + (size_t)e * (H_ * TWO_FFN),
                       H_, TWO_FFN, r0, c0, tile, tid);
        return;
    }
    if (bx < NB_T1 + NB_T2) {
        // w2: R=1408, C=1024; ctiles=16, rtiles=22
        int b2 = bx - NB_T1;
        int e = b2 / (16 * 22), rem = b2 % (16 * 22);
        int c0 = (rem % 16) * 64, r0 = (rem / 16) * 64;
        transpose_body(w2 + (size_t)e * (FFN_ * H_), w2bt + (size_t)e * (FFN_ * H_),
                       FFN_, H_, r0, c0, tile, tid);
        return;
    }
    // convert + gate (no global atomics)
    int cb = bx - (NB_T1 + NB_T2);
    int wid = tid >> 6, lane = tid & 63;
    int t = cb * 4 + wid;
    const float* xr = hs + xrow_off(t);
    unsigned short* xo = xb + (size_t)t * H_;
    float acc[E_];
#pragma unroll
    for (int e = 0; e < E_; e++) acc[e] = 0.f;
#pragma unroll
    for (int p = 0; p < 4; p++) {
        int h = p * 256 + lane * 4;
        const float4 v = *(const float4*)(xr + h);
        unsigned short o[4] = { f2bf(v.x), f2bf(v.y), f2bf(v.z), f2bf(v.w) };
        *(uint2*)(xo + h) = *(const uint2*)o;
#pragma unroll
        for (int e = 0; e < E_; e++) {
            const float4 g = *(const float4*)(gw + e * H_ + h);
            acc[e] += v.x * g.x + v.y * g.y + v.z * g.z + v.w * g.w;
        }
    }
#pragma unroll
    for (int e = 0; e < E_; e++)
        for (int off = 32; off > 0; off >>= 1) acc[e] += __shfl_down(acc[e], off);
    if (lane == 0) {
        float l0 = -1e30f, l1 = -1e30f; int i0 = 0, i1 = 0;
#pragma unroll
        for (int e = 0; e < E_; e++) {
            float v = acc[e];
            if (v > l0)      { l1 = l0; i1 = i0; l0 = v; i0 = e; }
            else if (v > l1) { l1 = v;  i1 = e; }
        }
        float p1 = expf(l1 - l0);                 // p0 = 1
        float w0 = 1.f / (1.f + p1);
        float w1s = 1.f - w0;
        topkI[2 * t] = i0; topkI[2 * t + 1] = i1;
        topkW[2 * t] = w0; topkW[2 * t + 1] = w1s;
    }
}

// ---------- 2. fused histogram + route + assign (one block) ----------
// ctrl ints: [40+e]=ntile(e)  [48+e]=slotBase(e)
__global__ void k_routeassign(const int* __restrict__ topkI, const float* __restrict__ topkW,
                              int* __restrict__ ctrl, int* __restrict__ perm,
                              int* __restrict__ slotOfTok) {
    __shared__ int s_wcnt[4][E_];
    __shared__ int s_base[E_];
    __shared__ int s_cur[E_];
    int tid = threadIdx.x, wid = tid >> 6, lane = tid & 63;
    int cnt[E_];
#pragma unroll
    for (int j = 0; j < E_; j++) cnt[j] = 0;
    for (int i = tid; i < 2 * T_; i += 256) {
        int e = topkI[i];
#pragma unroll
        for (int j = 0; j < E_; j++) cnt[j] += (e == j);
    }
#pragma unroll
    for (int j = 0; j < E_; j++)
        for (int off = 32; off > 0; off >>= 1) cnt[j] += __shfl_down(cnt[j], off);
    if (lane == 0) {
#pragma unroll
        for (int j = 0; j < E_; j++) s_wcnt[wid][j] = cnt[j];
    }
    __syncthreads();
    if (tid == 0) {
        int b = 0;
        for (int e = 0; e < E_; e++) {
            int n = s_wcnt[0][e] + s_wcnt[1][e] + s_wcnt[2][e] + s_wcnt[3][e];
            int ntile = (n + 127) >> 7;
            s_base[e] = b;
            ctrl[40 + e] = ntile;
            ctrl[48 + e] = b;
            b += ntile * 128;
        }
#pragma unroll
        for (int e = 0; e < E_; e++) s_cur[e] = 0;
    }
    __syncthreads();
    for (int s = tid; s < MAXSLOTS; s += 256) perm[s] = 0;   // padded slots -> token 0 (safe)
    __syncthreads();
    for (int t = tid; t < T_; t += 256) {
#pragma unroll
        for (int k = 0; k < 2; k++) {
            int e = topkI[2 * t + k];
            int pos = atomicAdd(&s_cur[e], 1);   // LDS atomic
            int slot = s_base[e] + pos;
            perm[slot] = t;
            slotOfTok[2 * t + k] = slot;
        }
    }
}

// ---------- 3. GEMM1 + fused swiglu epilogue ----------
// Grid: x = e + 8*ct (176), y = tile-in-expert (16): same (e,ct) => same XCD => B-slice L2 reuse.
__global__ __launch_bounds__(256) void k_gemm1(
    const unsigned short* __restrict__ xb, const unsigned short* __restrict__ w1bt,
    const int* __restrict__ ctrl, const int* __restrict__ perm,
    unsigned short* __restrict__ A2) {
    int e  = blockIdx.x & 7;
    int ct = blockIdx.x >> 3;                   // 0..21
    int ti = blockIdx.y;
    if (ti >= ctrl[40 + e]) return;
    int slot0 = ctrl[48 + e] + ti * 128;
    __shared__ __align__(16) unsigned short smem[2 * 128 * 64];   // As | Bs, reused as fp32 upLds
    unsigned short* As = smem;
    unsigned short* Bs = smem + 128 * 64;
    int tid = threadIdx.x, wid = tid >> 6, lane = tid & 63;

    const unsigned short* aPtr[4];
    const unsigned short* bPtr[4];
    unsigned short* lA[4];
    unsigned short* lB[4];
#pragma unroll
    for (int i = 0; i < 4; i++) {
        int c = (wid * 4 + i) * 64 + lane;      // chunk id 0..1023
        int r = c >> 3;
        int qd = (c & 7) ^ (r & 7);             // XOR swizzle
        int col8 = qd * 8;
        int tok = perm[slot0 + r];
        int gr = (r < 64) ? (ct * 64 + r) : (FFN_ + ct * 64 + (r - 64));  // gate/up rows
        aPtr[i] = xb + (size_t)tok * H_ + col8;
        bPtr[i] = w1bt + ((size_t)e * TWO_FFN + gr) * H_ + col8;
        lA[i] = As + (size_t)c * 8;
        lB[i] = Bs + (size_t)c * 8;
    }
    f32x4 acc[4][4];
#pragma unroll
    for (int mi = 0; mi < 4; mi++)
#pragma unroll
        for (int ni = 0; ni < 4; ni++) acc[mi][ni] = (f32x4){0.f, 0.f, 0.f, 0.f};
    int wm = wid & 1, wn = wid >> 1;
    int rowB = wm * 64, colB = wn * 64;
    int sw = (lane & 7) << 3;

    for (int k0 = 0; k0 < H_; k0 += 64) {
#pragma unroll
        for (int i = 0; i < 4; i++) { async16(aPtr[i] + k0, lA[i]); async16(bPtr[i] + k0, lB[i]); }
        __syncthreads();
#pragma unroll
        for (int kk = 0; kk < 64; kk += 32) {
            int kr = (kk + ((lane >> 4) << 3)) ^ sw;
            s16x8 af[4], bf[4];
#pragma unroll
            for (int mi = 0; mi < 4; mi++) af[mi] = *(const s16x8*)&As[(rowB + mi * 16 + (lane & 15)) * 64 + kr];
#pragma unroll
            for (int ni = 0; ni < 4; ni++) bf[ni] = *(const s16x8*)&Bs[(colB + ni * 16 + (lane & 15)) * 64 + kr];
#pragma unroll
            for (int mi = 0; mi < 4; mi++)
#pragma unroll
                for (int ni = 0; ni < 4; ni++)
                    acc[mi][ni] = __builtin_amdgcn_mfma_f32_16x16x32_bf16(af[mi], bf[ni], acc[mi][ni], 0, 0, 0);
        }
        __syncthreads();
    }
    // ---- fused swiglu epilogue ----
    float* upLds = (float*)smem;                // 128 x 64 fp32 = 32 KB
    if (wn == 1) {
#pragma unroll
        for (int mi = 0; mi < 4; mi++)
#pragma unroll
            for (int ni = 0; ni < 4; ni++)
#pragma unroll
                for (int r = 0; r < 4; r++) {
                    int m = rowB + mi * 16 + (lane >> 4) * 4 + r;
                    int u = ni * 16 + (lane & 15);
                    upLds[m * 64 + u] = acc[mi][ni][r];
                }
    }
    __syncthreads();
    if (wn == 0) {
#pragma unroll
        for (int mi = 0; mi < 4; mi++)
#pragma unroll
            for (int r = 0; r < 4; r++) {
                int m = rowB + mi * 16 + (lane >> 4) * 4 + r;
                unsigned short* arow = A2 + (size_t)(slot0 + m) * FFN_ + ct * 64;
#pragma unroll
                for (int ni = 0; ni < 4; ni++) {
                    int gl = ni * 16 + (lane & 15);
                    float g = acc[mi][ni][r];
                    float u = upLds[m * 64 + gl];
                    float s = g / (1.f + expf(-g));
                    arow[gl] = f2bf(s * u);
                }
            }
    }
}

// ---------- 4. GEMM2 (split-K=2): A2[128,1408] @ w2bt^T -> Yp bf16 partials ----------
__global__ __launch_bounds__(256) void k_gemm2(
    const unsigned short* __restrict__ A2, const unsigned short* __restrict__ w2bt,
    const int* __restrict__ ctrl, unsigned short* __restrict__ Yp) {
    int e  = blockIdx.x & 7;
    int ct = blockIdx.x >> 3;                   // 0..7
    int ti = blockIdx.y;
    if (ti >= ctrl[40 + e]) return;
    int slot0 = ctrl[48 + e] + ti * 128;
    int ks    = blockIdx.z;
    __shared__ __align__(16) unsigned short As[128 * 64];
    __shared__ __align__(16) unsigned short Bs[128 * 64];
    int tid = threadIdx.x, wid = tid >> 6, lane = tid & 63;

    const unsigned short* aPtr[4];
    const unsigned short* bPtr[4];
    unsigned short* lA[4];
    unsigned short* lB[4];
#pragma unroll
    for (int i = 0; i < 4; i++) {
        int c = (wid * 4 + i) * 64 + lane;
        int r = c >> 3;
        int qd = (c & 7) ^ (r & 7);
        int col8 = qd * 8;
        aPtr[i] = A2 + (size_t)(slot0 + r) * FFN_ + col8;
        bPtr[i] = w2bt + ((size_t)e * H_ + ct * 128 + r) * FFN_ + col8;
        lA[i] = As + (size_t)c * 8;
        lB[i] = Bs + (size_t)c * 8;
    }
    f32x4 acc[4][4];
#pragma unroll
    for (int mi = 0; mi < 4; mi++)
#pragma unroll
        for (int ni = 0; ni < 4; ni++) acc[mi][ni] = (f32x4){0.f, 0.f, 0.f, 0.f};
    int wm = wid & 1, wn = wid >> 1;
    int rowB = wm * 64, colB = wn * 64;
    int sw = (lane & 7) << 3;

    int kbeg = ks * (FFN_ / 2), kend = kbeg + FFN_ / 2;   // 11 steps each
    for (int k0 = kbeg; k0 < kend; k0 += 64) {
#pragma unroll
        for (int i = 0; i < 4; i++) { async16(aPtr[i] + k0, lA[i]); async16(bPtr[i] + k0, lB[i]); }
        __syncthreads();
#pragma unroll
        for (int kk = 0; kk < 64; kk += 32) {
            int kr = (kk + ((lane >> 4) << 3)) ^ sw;
            s16x8 af[4], bf[4];
#pragma unroll
            for (int mi = 0; mi < 4; mi++) af[mi] = *(const s16x8*)&As[(rowB + mi * 16 + (lane & 15)) * 64 + kr];
#pragma unroll
            for (int ni = 0; ni < 4; ni++) bf[ni] = *(const s16x8*)&Bs[(colB + ni * 16 + (lane & 15)) * 64 + kr];
#pragma unroll
            for (int mi = 0; mi < 4; mi++)
#pragma unroll
                for (int ni = 0; ni < 4; ni++)
                    acc[mi][ni] = __builtin_amdgcn_mfma_f32_16x16x32_bf16(af[mi], bf[ni], acc[mi][ni], 0, 0, 0);
        }
        __syncthreads();
    }
    unsigned short* yp = Yp + (size_t)ks * MAXSLOTS * H_;
#pragma unroll
    for (int mi = 0; mi < 4; mi++)
#pragma unroll
        for (int r = 0; r < 4; r++) {
            int m = rowB + mi * 16 + (lane >> 4) * 4 + r;
#pragma unroll
            for (int ni = 0; ni < 4; ni++) {
                int n = colB + ni * 16 + (lane & 15);
                yp[(size_t)(slot0 + m) * H_ + ct * 128 + n] = f2bf(acc[mi][ni][r]);
            }
        }
}

// ---------- 5. combine (bf16 partials) ----------
__global__ void k_combine(const unsigned short* __restrict__ Yp, const int* __restrict__ slotOfTok,
                          const float* __restrict__ topkW, float* __restrict__ out) {
    int t = blockIdx.x;
    int h = threadIdx.x * 4;
    int sA = slotOfTok[2 * t], sB = slotOfTok[2 * t + 1];
    float wA = topkW[2 * t],   wB = topkW[2 * t + 1];
    const unsigned short* pA0 = Yp + (size_t)sA * H_ + h;
    const unsigned short* pA1 = Yp + ((size_t)MAXSLOTS + sA) * H_ + h;
    const unsigned short* pB0 = Yp + (size_t)sB * H_ + h;
    const unsigned short* pB1 = Yp + ((size_t)MAXSLOTS + sB) * H_ + h;
    unsigned short a0[4], a1[4], b0[4], b1[4];
    *(uint2*)a0 = *(const uint2*)pA0;
    *(uint2*)a1 = *(const uint2*)pA1;
    *(uint2*)b0 = *(const uint2*)pB0;
    *(uint2*)b1 = *(const uint2*)pB1;
    float4 r;
    float* rp = (float*)&r;
#pragma unroll
    for (int i = 0; i < 4; i++) {
        float av = __uint_as_float(((unsigned)a0[i]) << 16) + __uint_as_float(((unsigned)a1[i]) << 16);
        float bv = __uint_as_float(((unsigned)b0[i]) << 16) + __uint_as_float(((unsigned)b1[i]) << 16);
        rp[i] = wA * av + wB * bv;
    }
    *(float4*)(out + xrow_off(t) + h) = r;
}

extern "C" void kernel_launch(void* const* d_in, const int* in_sizes, int n_in,
                              void* d_out, int out_size, void* d_ws, size_t ws_size,
                              hipStream_t stream) {
    (void)in_sizes; (void)n_in; (void)ws_size; (void)out_size;
    const float* hs = (const float*)d_in[0];
    const float* gw = (const float*)d_in[1];
    const float* w1 = (const float*)d_in[2];
    const float* w2 = (const float*)d_in[3];
    float* out = (float*)d_out;
    char* ws = (char*)d_ws;

    int*            ctrl   = (int*)ws;                                  // 1 KB
    int*            topkI  = (int*)(ws + (16u << 10));                  // 16 KB
    float*          topkW  = (float*)(ws + (48u << 10));                // 16 KB
    int*            perm   = (int*)(ws + (80u << 10));                  // 20 KB
    int*            slotOfTok = (int*)(ws + (144u << 10));              // 16 KB
    unsigned short* xb    = (unsigned short*)(ws + (1ull  << 20));      // 4 MiB
    unsigned short* w1bt  = (unsigned short*)(ws + (5ull  << 20));      // 44 MiB (dead after gemm1)
    unsigned short* Yp    = (unsigned short*)(ws + (5ull << 20));       // 20 MiB — ALIASES w1bt
    unsigned short* w2bt  = (unsigned short*)(ws + (49ull << 20));      // 22 MiB
    unsigned short* A2    = (unsigned short*)(ws + (71ull << 20));      // 13.75 MiB -> end ~85 MiB

    k_prep<<<NB_PREP, 256, 0, stream>>>(hs, gw, w1, w2, xb, w1bt, w2bt, topkI, topkW);
    k_routeassign<<<1, 256, 0, stream>>>(topkI, topkW, ctrl, perm, slotOfTok);
    k_gemm1<<<dim3(8 * (FFN_ / 64), 16), 256, 0, stream>>>(xb, w1bt, ctrl, perm, A2);
    k_gemm2<<<dim3(8 * (H_ / 128), 16, 2), 256, 0, stream>>>(A2, w2bt, ctrl, Yp);
    k_combine<<<2048, 256, 0, stream>>>(Yp, slotOfTok, topkW, out);
}